// Round 8
// baseline (340.270 us; speedup 1.0000x reference)
//
#include <hip/hip_runtime.h>

// RubiksShift forward: out[n,c,i,j] = bilinear(x[n,c], i+sh[c], j+sw[c]),
// zero outside the map. |shift| < 1 so floor(shift) ∈ {-1, 0}.
//
// r8: pure-stream shape. 2 output rows per thread share the middle source
// row: 3 aligned f4 loads : 2 f4 stores. The 5th horizontal tap comes from
// the neighbor LANE via __shfl_up/down (no scalar loads at all). Lanes are
// packed 32-per-group (28 active f4 cols), so shuffles stay in-group; the
// only cross-boundary shuffles hit taps already zeroed by the col masks.
// No LDS, no barriers, plain stores.

#define NDIM 16
#define CDIM 256
#define HDIM 112
#define WDIM 112

using f32x4 = __attribute__((ext_vector_type(4))) float;

__device__ __forceinline__ f32x4 ld4(const float* p) {
    return *reinterpret_cast<const f32x4*>(p);
}

__global__ __launch_bounds__(256) void rubiks_shift_fwd(
    const float* __restrict__ x,      // [N, C, H, W]
    const float* __restrict__ shift,  // [2, C]
    float* __restrict__ out)          // [N, C, H, W]
{
    constexpr int HW = HDIM * WDIM;    // 12544

    const int plane = blockIdx.x;      // one block per (n,c) plane
    const int tid   = threadIdx.x;
    const int c     = plane & (CDIM - 1);

    // ---- block-uniform per-channel decode (validated r5/r7) ----
    const float sh  = shift[c];
    const float sw  = shift[CDIM + c];
    const float flh = floorf(sh);
    const float flw = floorf(sw);
    const float frh = sh - flh;        // [0,1)
    const float frw = sw - flw;
    const int  iflh = (int)flh;        // -1 or 0
    const bool neg  = flw < 0.0f;      // floor(sw) == -1 (block-uniform)
    const float ww1 = frw, ww0 = 1.0f - frw;
    const float wh1 = frh, wh0 = 1.0f - frh;

    // 32-lane groups: g = row-pair lane-group, j4 = f4 column (active < 28).
    const int g    = tid >> 5;         // 0..7
    const int j4   = tid & 31;         // 0..31
    const bool act = j4 < 28;
    const int j4c  = act ? j4 : 27;    // idle lanes shadow col 27 (feeds shfl)
    const int j    = j4c * 4;

    const float* __restrict__ pb = x   + (size_t)plane * HW + j;
    float* __restrict__       po = out + (size_t)plane * HW + j;

    // row-pairs rp = g + 8u, u = 0..6  (covers all 56 row pairs)
    // 2-deep register pipeline: prefetch next rp's 3 rows during compute.
    f32x4 A, B, C;                     // source rows r, r+1, r+2
    {
        const int r  = 2 * g + iflh;
        const int ra = max(r, 0);
        const int rc = min(r + 2, HDIM - 1);
        A = ld4(pb + ra * WDIM);
        B = ld4(pb + (r + 1) * WDIM);
        C = ld4(pb + rc * WDIM);
    }

    for (int u = 0; u < 7; ++u) {
        const int rp = g + 8 * u;
        const int r  = 2 * rp + iflh;

        f32x4 A2, B2, C2;
        if (u < 6) {                   // issue next tile's loads early (T14)
            const int rn = 2 * (rp + 8) + iflh;     // >= 15, no low clamp
            const int rc = min(rn + 2, HDIM - 1);
            A2 = ld4(pb + rn * WDIM);
            B2 = ld4(pb + (rn + 1) * WDIM);
            C2 = ld4(pb + rc * WDIM);
        }

        // Neighbor-lane 5th tap (single float per row).
        float sA, sB, sC;
        if (neg) {                     // tap j-1 = lane-1's F.w
            sA = __shfl_up(A[3], 1);
            sB = __shfl_up(B[3], 1);
            sC = __shfl_up(C[3], 1);
        } else {                       // tap j+4 = lane+1's F.x
            sA = __shfl_down(A[0], 1);
            sB = __shfl_down(B[0], 1);
            sC = __shfl_down(C[0], 1);
        }
        const bool edge = neg ? (j4c == 0) : (j4c == 27);  // col -1 / col 112
        if (edge) { sA = 0.0f; sB = 0.0f; sC = 0.0f; }

        float tA[5], tB[5], tC[5];
        if (neg) {   // taps j-1..j+3
            tA[0]=sA; tA[1]=A[0]; tA[2]=A[1]; tA[3]=A[2]; tA[4]=A[3];
            tB[0]=sB; tB[1]=B[0]; tB[2]=B[1]; tB[3]=B[2]; tB[4]=B[3];
            tC[0]=sC; tC[1]=C[0]; tC[2]=C[1]; tC[3]=C[2]; tC[4]=C[3];
        } else {     // taps j..j+4
            tA[0]=A[0]; tA[1]=A[1]; tA[2]=A[2]; tA[3]=A[3]; tA[4]=sA;
            tB[0]=B[0]; tB[1]=B[1]; tB[2]=B[2]; tB[3]=B[3]; tB[4]=sB;
            tC[0]=C[0]; tC[1]=C[1]; tC[2]=C[2]; tC[3]=C[3]; tC[4]=sC;
        }

        float hA[4], hB[4], hC[4];     // horizontal lerps (middle row shared)
        #pragma unroll
        for (int k = 0; k < 4; ++k) {
            hA[k] = ww0 * tA[k] + ww1 * tA[k + 1];
            hB[k] = ww0 * tB[k] + ww1 * tB[k + 1];
            hC[k] = ww0 * tC[k] + ww1 * tC[k + 1];
        }

        // Row-validity folded into vertical weights.
        const float w00 = (r >= 0)           ? wh0 : 0.0f;  // neg, rp==0
        const float w11 = (r + 2 < HDIM)     ? wh1 : 0.0f;  // pos, rp==55

        f32x4 o0, o1;
        #pragma unroll
        for (int k = 0; k < 4; ++k) {
            o0[k] = w00 * hA[k] + wh1 * hB[k];   // out row 2rp
            o1[k] = wh0 * hB[k] + w11 * hC[k];   // out row 2rp+1
        }

        if (act) {
            *reinterpret_cast<f32x4*>(po + (2 * rp)     * WDIM) = o0;
            *reinterpret_cast<f32x4*>(po + (2 * rp + 1) * WDIM) = o1;
        }

        A = A2; B = B2; C = C2;
    }
}

extern "C" void kernel_launch(void* const* d_in, const int* in_sizes, int n_in,
                              void* d_out, int out_size, void* d_ws, size_t ws_size,
                              hipStream_t stream) {
    const float* x     = (const float*)d_in[0];
    const float* shift = (const float*)d_in[1];
    float* out         = (float*)d_out;

    constexpr int grid = NDIM * CDIM;   // 4096 blocks, one per plane
    rubiks_shift_fwd<<<grid, 256, 0, stream>>>(x, shift, out);
}